// Round 7
// baseline (1053.284 us; speedup 1.0000x reference)
//
#include <hip/hip_runtime.h>
#include <math.h>

#define T_TOK 16384
#define D_DIM 2048
#define NSLOT 64
#define H_DIM 1024
#define KSPLIT 8
#define KCH 256            // D_DIM / KSPLIT
#define TBLK 128           // tokens per logits block

// ---------------------------------------------------------------------------
// Kernel 1: partial logits. Block: 128 tok x 64 slots, 256 thr, 4x8 regtile.
// Grid (128 tb, 8 ksplit). 64-k stages, T14 reg-prefetch double buffer.
// LDS 48 KB -> 3 blocks/CU. Block (0,0) zeroes the pz4 atomic bins.
// ---------------------------------------------------------------------------
__global__ __launch_bounds__(256) void k_logits(const float* __restrict__ x,
                                                const float* __restrict__ Wd,
                                                float* __restrict__ plog,
                                                float* __restrict__ pz4) {
    __shared__ float xs[128 * 64];     // 128 rows x 16 f4, XOR-swizzled
    __shared__ float ws[64 * 64];      // 64 rows x 16 f4, XOR-swizzled
    const int tid = threadIdx.x;
    if (blockIdx.x == 0 && blockIdx.y == 0) pz4[tid] = 0.f;
    const int tblk = blockIdx.x * TBLK;
    const int koff = blockIdx.y * KCH;
    const int tq = tid >> 3;     // 0..31
    const int sg = tid & 7;      // 0..7
    float acc[4][8] = {};
    float4 px[8], pw[4];

    // stage-load address components (constant across stages)
    const int xt = tid >> 4, xc = tid & 15;          // +32 rows per ii

#define LOADSTAGE(KST)                                                        \
    {                                                                         \
        const int kb = koff + (KST) * 64;                                     \
        _Pragma("unroll")                                                     \
        for (int ii = 0; ii < 8; ++ii)                                        \
            px[ii] = *(const float4*)&x[(size_t)(tblk + xt + ii * 16) * D_DIM \
                                        + kb + xc * 4];                       \
        _Pragma("unroll")                                                     \
        for (int ii = 0; ii < 4; ++ii)                                        \
            pw[ii] = *(const float4*)&Wd[(size_t)(xt + ii * 16) * D_DIM       \
                                         + kb + xc * 4];                      \
    }

#define WRITESTAGE()                                                          \
    {                                                                         \
        _Pragma("unroll")                                                     \
        for (int ii = 0; ii < 8; ++ii) {                                      \
            int t = xt + ii * 16;                                             \
            *(float4*)&xs[t * 64 + ((xc ^ (t & 7)) << 2)] = px[ii];           \
        }                                                                     \
        _Pragma("unroll")                                                     \
        for (int ii = 0; ii < 4; ++ii) {                                      \
            int s = xt + ii * 16;                                             \
            *(float4*)&ws[s * 64 + ((xc ^ (s & 7)) << 2)] = pw[ii];           \
        }                                                                     \
    }

    LOADSTAGE(0);
    WRITESTAGE();
    __syncthreads();
    for (int kst = 0; kst < 4; ++kst) {
        if (kst < 3) LOADSTAGE(kst + 1);          // in flight during compute
        #pragma unroll
        for (int c = 0; c < 16; ++c) {
            float4 wv[8];
            #pragma unroll
            for (int j = 0; j < 8; ++j)
                wv[j] = *(const float4*)&ws[(sg + 8 * j) * 64 + ((c ^ sg) << 2)];
            #pragma unroll
            for (int i = 0; i < 4; ++i) {
                float4 xv = *(const float4*)&xs[(tq + 32 * i) * 64
                                                + ((c ^ (tq & 7)) << 2)];
                #pragma unroll
                for (int j = 0; j < 8; ++j)
                    acc[i][j] += xv.x * wv[j].x + xv.y * wv[j].y +
                                 xv.z * wv[j].z + xv.w * wv[j].w;
            }
        }
        if (kst < 3) {
            __syncthreads();                       // readers done
            WRITESTAGE();                          // regs -> LDS
            __syncthreads();                       // writes visible
        }
    }
#undef LOADSTAGE
#undef WRITESTAGE
    const size_t ksbase = (size_t)blockIdx.y * T_TOK;
    #pragma unroll
    for (int i = 0; i < 4; ++i)
        #pragma unroll
        for (int j = 0; j < 8; ++j)
            plog[(ksbase + tblk + tq + 32 * i) * NSLOT + sg + 8 * j] = acc[i][j];
}

// ---------------------------------------------------------------------------
// Kernel 2: sum K-splits -> E = exp(logits); column sums via atomic bins.
// grid 512 (32 tokens each), block 256.
// ---------------------------------------------------------------------------
__global__ __launch_bounds__(256) void k_lsum(const float* __restrict__ plog,
                                              float* __restrict__ elog,
                                              float* __restrict__ pz4) {
    __shared__ float zsh[4][64];
    const int tid = threadIdx.x;
    const int s = tid & 63, rq = tid >> 6;
    const int j0 = blockIdx.x * 32;
    float zacc = 0.f;
    #pragma unroll
    for (int i = 0; i < 8; ++i) {
        int r = j0 + rq * 8 + i;
        float v = 0.f;
        #pragma unroll
        for (int ks = 0; ks < KSPLIT; ++ks)
            v += plog[((size_t)ks * T_TOK + r) * NSLOT + s];
        float e = __expf(v);
        elog[(size_t)r * NSLOT + s] = e;
        zacc += e;
    }
    zsh[rq][s] = zacc;
    __syncthreads();
    if (tid < 64)
        atomicAdd(&pz4[(blockIdx.x & 3) * 64 + tid],
                  zsh[0][tid] + zsh[1][tid] + zsh[2][tid] + zsh[3][tid]);
}

// ---------------------------------------------------------------------------
// Kernel 3: unnormalized slot-input partials: partial[tc][s][d] =
// sum_{t in chunk} E[t][s] * x[t][d]. grid (8 d-tiles of 256, 64 t-chunks).
// T14 reg-prefetch double buffer over the 8 sub-stages.
// ---------------------------------------------------------------------------
__global__ __launch_bounds__(256) void k_slot(const float* __restrict__ x,
        const float* __restrict__ elog, float* __restrict__ partial) {
    __shared__ float xs[32][256];
    __shared__ float pls[32][64];
    const int tid = threadIdx.x;
    const int d0 = blockIdx.x * 256;
    const int tc0 = blockIdx.y * 256;
    const int dg = tid & 31, sgq = tid >> 5;
    const int xr = tid >> 6, xc = tid & 63;        // x stage: +4 rows per ii
    const int pr = tid >> 4, pc = tid & 15;        // pls stage: +16 rows per ii
    float4 acc0[8] = {}, acc1[8] = {};
    float4 gx[8], gp[2];

#define SLOADSTAGE(SUB)                                                       \
    {                                                                         \
        const int t0 = tc0 + (SUB) * 32;                                      \
        _Pragma("unroll")                                                     \
        for (int ii = 0; ii < 8; ++ii)                                        \
            gx[ii] = *(const float4*)&x[(size_t)(t0 + xr + ii * 4) * D_DIM    \
                                        + d0 + xc * 4];                       \
        _Pragma("unroll")                                                     \
        for (int ii = 0; ii < 2; ++ii)                                        \
            gp[ii] = *(const float4*)&elog[(size_t)(t0 + pr + ii * 16)        \
                                           * NSLOT + pc * 4];                 \
    }

#define SWRITESTAGE()                                                         \
    {                                                                         \
        _Pragma("unroll")                                                     \
        for (int ii = 0; ii < 8; ++ii)                                        \
            *(float4*)&xs[xr + ii * 4][xc * 4] = gx[ii];                      \
        _Pragma("unroll")                                                     \
        for (int ii = 0; ii < 2; ++ii)                                        \
            *(float4*)&pls[pr + ii * 16][pc * 4] = gp[ii];                    \
    }

    SLOADSTAGE(0);
    SWRITESTAGE();
    __syncthreads();
    for (int sub = 0; sub < 8; ++sub) {
        if (sub < 7) SLOADSTAGE(sub + 1);
        for (int t = 0; t < 32; ++t) {
            float4 xv0 = *(const float4*)&xs[t][dg * 4];
            float4 xv1 = *(const float4*)&xs[t][128 + dg * 4];
            #pragma unroll
            for (int i = 0; i < 8; ++i) {
                float p = pls[t][sgq * 8 + i];
                acc0[i].x += p * xv0.x; acc0[i].y += p * xv0.y;
                acc0[i].z += p * xv0.z; acc0[i].w += p * xv0.w;
                acc1[i].x += p * xv1.x; acc1[i].y += p * xv1.y;
                acc1[i].z += p * xv1.z; acc1[i].w += p * xv1.w;
            }
        }
        if (sub < 7) {
            __syncthreads();
            SWRITESTAGE();
            __syncthreads();
        }
    }
#undef SLOADSTAGE
#undef SWRITESTAGE
    #pragma unroll
    for (int i = 0; i < 8; ++i) {
        int s = sgq * 8 + i;
        *(float4*)&partial[((size_t)blockIdx.y * NSLOT + s) * D_DIM + d0 + dg * 4] = acc0[i];
        *(float4*)&partial[((size_t)blockIdx.y * NSLOT + s) * D_DIM + d0 + 128 + dg * 4] = acc1[i];
    }
}

// ---------------------------------------------------------------------------
// Kernel 4: slot_in = (1/Z_s) * sum_c partial. grid 128, block 256.
// ---------------------------------------------------------------------------
__global__ __launch_bounds__(256) void k_sred(const float* __restrict__ partial,
                                              const float* __restrict__ pz4,
                                              float* __restrict__ slot_in) {
    const size_t idx = (size_t)blockIdx.x * 256 + threadIdx.x;   // float4 index
    const int s = (int)(idx >> 9);                               // 512 f4 per slot
    const float iz = 1.f / (pz4[s] + pz4[64 + s] + pz4[128 + s] + pz4[192 + s]);
    const float4* p4 = (const float4*)partial;
    float4 a = {0.f, 0.f, 0.f, 0.f};
    for (int c0 = 0; c0 < 8; ++c0) {
        float4 v[8];
        #pragma unroll
        for (int j = 0; j < 8; ++j)
            v[j] = p4[(size_t)(c0 * 8 + j) * (NSLOT * D_DIM / 4) + idx];
        #pragma unroll
        for (int j = 0; j < 8; ++j) {
            a.x += v[j].x; a.y += v[j].y; a.z += v[j].z; a.w += v[j].w;
        }
    }
    a.x *= iz; a.y *= iz; a.z *= iz; a.w *= iz;
    ((float4*)slot_in)[idx] = a;
}

// ---------------------------------------------------------------------------
// Kernel 5: h = gelu(W1 @ slot_in + b1). One wave per row, grid 16384.
// ---------------------------------------------------------------------------
__global__ __launch_bounds__(256) void k_mlp1(const float* __restrict__ W1,
                                              const float* __restrict__ b1,
                                              const float* __restrict__ slot_in,
                                              float* __restrict__ h) {
    const int wave = threadIdx.x >> 6, lane = threadIdx.x & 63;
    const int row = blockIdx.x * 4 + wave;           // e*1024 + j
    const int e = row >> 10;
    const float* wr = W1 + (size_t)row * D_DIM;
    const float* xr = slot_in + (size_t)e * D_DIM;
    float acc = 0.f;
    #pragma unroll
    for (int i = 0; i < 8; ++i) {
        int k = (lane + i * 64) * 4;
        float4 w4 = *(const float4*)(wr + k);
        float4 x4 = *(const float4*)(xr + k);
        acc += w4.x * x4.x + w4.y * x4.y + w4.z * x4.z + w4.w * x4.w;
    }
    #pragma unroll
    for (int off = 32; off; off >>= 1) acc += __shfl_xor(acc, off);
    if (lane == 0) {
        float v = acc + b1[row];
        h[row] = 0.5f * v * (1.f + erff(v * 0.70710678118654752f));
    }
}

// Kernel 6: slot_out = W2 @ h + b2. One wave per row, grid 32768.
__global__ __launch_bounds__(256) void k_mlp2(const float* __restrict__ W2,
                                              const float* __restrict__ b2,
                                              const float* __restrict__ h,
                                              float* __restrict__ slot_out) {
    const int wave = threadIdx.x >> 6, lane = threadIdx.x & 63;
    const int row = blockIdx.x * 4 + wave;           // e*2048 + d
    const int e = row >> 11;
    const float* wr = W2 + (size_t)row * H_DIM;
    const float* xr = h + (size_t)e * H_DIM;
    float acc = 0.f;
    #pragma unroll
    for (int i = 0; i < 4; ++i) {
        int k = (lane + i * 64) * 4;
        float4 w4 = *(const float4*)(wr + k);
        float4 x4 = *(const float4*)(xr + k);
        acc += w4.x * x4.x + w4.y * x4.y + w4.z * x4.z + w4.w * x4.w;
    }
    #pragma unroll
    for (int off = 32; off; off >>= 1) acc += __shfl_xor(acc, off);
    if (lane == 0) slot_out[row] = acc + b2[row];
}

// ---------------------------------------------------------------------------
// Kernel 7: y[t] = (sum_s E[t][s]*so[s]) / (sum_s E[t][s]). Block 128x128.
// ---------------------------------------------------------------------------
__global__ __launch_bounds__(256) void k_combine(const float* __restrict__ elog,
                                                 const float* __restrict__ so,
                                                 float* __restrict__ y) {
    __shared__ float cl[128][68];
    __shared__ float sol[64][128];
    __shared__ float rinv[128];
    const int tid = threadIdx.x;
    const int d0 = blockIdx.x * 128;
    const int tb = blockIdx.y * 128;
    const int tq = tid >> 4;    // 0..15
    const int dgq = tid & 15;   // 0..15
    #pragma unroll
    for (int ii = 0; ii < 8; ++ii) {          // stage E: 128x64
        int fi = tid + ii * 256; int r = fi >> 4, s4 = fi & 15;
        *(float4*)&cl[r][s4 * 4] =
            *(const float4*)&elog[(size_t)(tb + r) * NSLOT + s4 * 4];
    }
    #pragma unroll
    for (int ii = 0; ii < 8; ++ii) {          // stage slot_out tile 64x128
        int fi = tid + ii * 256; int r = fi >> 5, c4 = fi & 31;
        *(float4*)&sol[r][c4 * 4] =
            *(const float4*)&so[(size_t)r * D_DIM + d0 + c4 * 4];
    }
    __syncthreads();
    if (tid < 128) {                          // row sums -> 1/Z_t
        float zs = 0.f;
        #pragma unroll
        for (int q = 0; q < 16; ++q) {
            float4 v = *(const float4*)&cl[tid][q * 4];
            zs += v.x + v.y + v.z + v.w;
        }
        rinv[tid] = 1.f / zs;
    }
    __syncthreads();
    float4 acc0[8] = {}, acc1[8] = {};
    for (int s = 0; s < 64; ++s) {
        float4 sv0 = *(const float4*)&sol[s][dgq * 4];
        float4 sv1 = *(const float4*)&sol[s][64 + dgq * 4];
        #pragma unroll
        for (int i = 0; i < 8; ++i) {
            float cv = cl[tq + 16 * i][s];
            acc0[i].x += cv * sv0.x; acc0[i].y += cv * sv0.y;
            acc0[i].z += cv * sv0.z; acc0[i].w += cv * sv0.w;
            acc1[i].x += cv * sv1.x; acc1[i].y += cv * sv1.y;
            acc1[i].z += cv * sv1.z; acc1[i].w += cv * sv1.w;
        }
    }
    #pragma unroll
    for (int i = 0; i < 8; ++i) {
        float rz = rinv[tq + 16 * i];
        acc0[i].x *= rz; acc0[i].y *= rz; acc0[i].z *= rz; acc0[i].w *= rz;
        acc1[i].x *= rz; acc1[i].y *= rz; acc1[i].z *= rz; acc1[i].w *= rz;
        *(float4*)&y[(size_t)(tb + tq + 16 * i) * D_DIM + d0 + dgq * 4] = acc0[i];
        *(float4*)&y[(size_t)(tb + tq + 16 * i) * D_DIM + d0 + 64 + dgq * 4] = acc1[i];
    }
}

// ---------------------------------------------------------------------------
extern "C" void kernel_launch(void* const* d_in, const int* in_sizes, int n_in,
                              void* d_out, int out_size, void* d_ws, size_t ws_size,
                              hipStream_t stream) {
    const float* x  = (const float*)d_in[0];
    const float* Wd = (const float*)d_in[1];
    const float* W1 = (const float*)d_in[2];
    const float* b1 = (const float*)d_in[3];
    const float* W2 = (const float*)d_in[4];
    const float* b2 = (const float*)d_in[5];
    float* y = (float*)d_out;

    float* w = (float*)d_ws;
    float* plog     = w;                                      // 8*16384*64
    float* elog     = plog + (size_t)KSPLIT * T_TOK * NSLOT;  // 16384*64
    float* pz4      = elog + (size_t)T_TOK * NSLOT;           // 256 bins
    float* partial  = pz4 + 256;                              // 64*64*2048
    float* slot_in  = partial + (size_t)64 * NSLOT * D_DIM;   // 64*2048
    float* h        = slot_in + (size_t)NSLOT * D_DIM;        // 64*1024
    float* slot_out = h + (size_t)NSLOT * H_DIM;              // 64*2048

    k_logits<<<dim3(T_TOK / TBLK, KSPLIT), 256, 0, stream>>>(x, Wd, plog, pz4);
    k_lsum<<<512, 256, 0, stream>>>(plog, elog, pz4);
    k_slot<<<dim3(8, 64), 256, 0, stream>>>(x, elog, partial);
    k_sred<<<128, 256, 0, stream>>>(partial, pz4, slot_in);
    k_mlp1<<<(NSLOT * H_DIM) / 4, 256, 0, stream>>>(W1, b1, slot_in, h);
    k_mlp2<<<(NSLOT * D_DIM) / 4, 256, 0, stream>>>(W2, b2, h, slot_out);
    k_combine<<<dim3(16, 128), 256, 0, stream>>>(elog, slot_out, y);
}

// Round 8
// 476.349 us; speedup vs baseline: 2.2112x; 2.2112x over previous
//
#include <hip/hip_runtime.h>
#include <math.h>

#define T_TOK 16384
#define D_DIM 2048
#define NSLOT 64
#define H_DIM 1024
#define KSPLIT 8
#define KCH 256            // D_DIM / KSPLIT
#define TBLK 128           // tokens per logits block

// ---------------------------------------------------------------------------
// Kernel 1: partial logits. Block: 128 tok x 64 slots, 256 thr, 4x8 regtile.
// Grid (128 tb, 8 ksplit). Block (0,0) also zeroes the pz4 atomic bins.
// (R6-proven form: single-buffered 32-k chunks, XOR-swizzled LDS.)
// ---------------------------------------------------------------------------
__global__ __launch_bounds__(256) void k_logits(const float* __restrict__ x,
                                                const float* __restrict__ Wd,
                                                float* __restrict__ plog,
                                                float* __restrict__ pz4) {
    __shared__ float xs[128][32];
    __shared__ float ws[64][32];
    const int tid = threadIdx.x;
    if (blockIdx.x == 0 && blockIdx.y == 0) pz4[tid] = 0.f;   // 256 bins
    const int tblk = blockIdx.x * TBLK;
    const int koff = blockIdx.y * KCH;
    const int tq = tid >> 3;     // 0..31
    const int sg = tid & 7;      // 0..7
    float acc[4][8] = {};

    for (int kc = 0; kc < KCH; kc += 32) {
        __syncthreads();
        #pragma unroll
        for (int ii = 0; ii < 4; ++ii) {          // xs: 1024 f4
            int fi = tid + ii * 256; int t = fi >> 3, c = fi & 7;
            *(float4*)&xs[t][(c ^ (t & 7)) << 2] =
                *(const float4*)&x[(size_t)(tblk + t) * D_DIM + koff + kc + c * 4];
        }
        #pragma unroll
        for (int ii = 0; ii < 2; ++ii) {          // ws: 512 f4
            int fi = tid + ii * 256; int s = fi >> 3, c = fi & 7;
            *(float4*)&ws[s][(c ^ (s & 7)) << 2] =
                *(const float4*)&Wd[(size_t)s * D_DIM + koff + kc + c * 4];
        }
        __syncthreads();
        #pragma unroll
        for (int c = 0; c < 8; ++c) {
            float4 wv[8];
            #pragma unroll
            for (int j = 0; j < 8; ++j)
                wv[j] = *(const float4*)&ws[sg + 8 * j][(c ^ sg) << 2];
            #pragma unroll
            for (int i = 0; i < 4; ++i) {
                float4 xv = *(const float4*)&xs[tq + 32 * i][(c ^ (tq & 7)) << 2];
                #pragma unroll
                for (int j = 0; j < 8; ++j)
                    acc[i][j] += xv.x * wv[j].x + xv.y * wv[j].y +
                                 xv.z * wv[j].z + xv.w * wv[j].w;
            }
        }
    }
    const size_t ksbase = (size_t)blockIdx.y * T_TOK;
    #pragma unroll
    for (int i = 0; i < 4; ++i)
        #pragma unroll
        for (int j = 0; j < 8; ++j)
            plog[(ksbase + tblk + tq + 32 * i) * NSLOT + sg + 8 * j] = acc[i][j];
}

// ---------------------------------------------------------------------------
// Kernel 2: sum K-splits -> E = exp(logits); column sums via atomic bins.
// grid 1024 (16 tokens each), block 256 -> 4 waves/SIMD.
// ---------------------------------------------------------------------------
__global__ __launch_bounds__(256) void k_lsum(const float* __restrict__ plog,
                                              float* __restrict__ elog,
                                              float* __restrict__ pz4) {
    __shared__ float zsh[4][64];
    const int tid = threadIdx.x;
    const int s = tid & 63, rq = tid >> 6;
    const int j0 = blockIdx.x * 16;
    float zacc = 0.f;
    #pragma unroll
    for (int i = 0; i < 4; ++i) {
        int r = j0 + rq * 4 + i;
        float v = 0.f;
        #pragma unroll
        for (int ks = 0; ks < KSPLIT; ++ks)
            v += plog[((size_t)ks * T_TOK + r) * NSLOT + s];
        float e = __expf(v);
        elog[(size_t)r * NSLOT + s] = e;
        zacc += e;
    }
    zsh[rq][s] = zacc;
    __syncthreads();
    if (tid < 64)
        atomicAdd(&pz4[(blockIdx.x & 3) * 64 + tid],
                  zsh[0][tid] + zsh[1][tid] + zsh[2][tid] + zsh[3][tid]);
}

// ---------------------------------------------------------------------------
// Kernel 3: unnormalized slot-input partials: partial[tc][s][d] =
// sum_{t in chunk} E[t][s] * x[t][d]. grid (8 d-tiles of 256, 64 t-chunks).
// (R6-proven form.)
// ---------------------------------------------------------------------------
__global__ __launch_bounds__(256) void k_slot(const float* __restrict__ x,
        const float* __restrict__ elog, float* __restrict__ partial) {
    __shared__ float xs[32][256];
    __shared__ float pls[32][64];
    const int tid = threadIdx.x;
    const int d0 = blockIdx.x * 256;
    const int tc0 = blockIdx.y * 256;
    const int dg = tid & 31, sgq = tid >> 5;
    float4 acc0[8] = {}, acc1[8] = {};

    for (int sub = 0; sub < 8; ++sub) {
        const int t0 = tc0 + sub * 32;
        __syncthreads();
        #pragma unroll
        for (int ii = 0; ii < 8; ++ii) {
            int fi = tid + ii * 256; int r = fi >> 6, c4 = fi & 63;
            *(float4*)&xs[r][c4 * 4] =
                *(const float4*)&x[(size_t)(t0 + r) * D_DIM + d0 + c4 * 4];
        }
        #pragma unroll
        for (int ii = 0; ii < 2; ++ii) {
            int fi = tid + ii * 256; int r = fi >> 4, s4 = fi & 15;
            *(float4*)&pls[r][s4 * 4] =
                *(const float4*)&elog[(size_t)(t0 + r) * NSLOT + s4 * 4];
        }
        __syncthreads();
        for (int t = 0; t < 32; ++t) {
            float4 xv0 = *(const float4*)&xs[t][dg * 4];
            float4 xv1 = *(const float4*)&xs[t][128 + dg * 4];
            #pragma unroll
            for (int i = 0; i < 8; ++i) {
                float p = pls[t][sgq * 8 + i];
                acc0[i].x += p * xv0.x; acc0[i].y += p * xv0.y;
                acc0[i].z += p * xv0.z; acc0[i].w += p * xv0.w;
                acc1[i].x += p * xv1.x; acc1[i].y += p * xv1.y;
                acc1[i].z += p * xv1.z; acc1[i].w += p * xv1.w;
            }
        }
    }
    #pragma unroll
    for (int i = 0; i < 8; ++i) {
        int s = sgq * 8 + i;
        *(float4*)&partial[((size_t)blockIdx.y * NSLOT + s) * D_DIM + d0 + dg * 4] = acc0[i];
        *(float4*)&partial[((size_t)blockIdx.y * NSLOT + s) * D_DIM + d0 + 128 + dg * 4] = acc1[i];
    }
}

// ---------------------------------------------------------------------------
// Kernel 4: slot_in = (1/Z_s) * sum_c partial. grid 512, block 256:
// 4 threads per f4-output (16 chunks each) + LDS combine -> 8 waves/CU.
// ---------------------------------------------------------------------------
__global__ __launch_bounds__(256) void k_sred(const float* __restrict__ partial,
                                              const float* __restrict__ pz4,
                                              float* __restrict__ slot_in) {
    __shared__ float4 red[256];
    const int tid = threadIdx.x;
    const int o = blockIdx.x * 64 + (tid & 63);       // f4 index, < 32768
    const int part = tid >> 6;                         // 0..3
    const float4* p4 = (const float4*)partial;
    float4 a = {0.f, 0.f, 0.f, 0.f};
    #pragma unroll
    for (int c0 = 0; c0 < 2; ++c0) {
        float4 v[8];
        #pragma unroll
        for (int j = 0; j < 8; ++j)
            v[j] = p4[(size_t)(part * 16 + c0 * 8 + j) * (NSLOT * D_DIM / 4) + o];
        #pragma unroll
        for (int j = 0; j < 8; ++j) {
            a.x += v[j].x; a.y += v[j].y; a.z += v[j].z; a.w += v[j].w;
        }
    }
    red[tid] = a;
    __syncthreads();
    if (tid < 64) {
        const int s = o >> 9;                          // 512 f4 per slot
        const float iz = 1.f / (pz4[s] + pz4[64 + s] + pz4[128 + s] + pz4[192 + s]);
        float4 b = red[tid];
        #pragma unroll
        for (int p = 1; p < 4; ++p) {
            float4 v = red[tid + p * 64];
            b.x += v.x; b.y += v.y; b.z += v.z; b.w += v.w;
        }
        b.x *= iz; b.y *= iz; b.z *= iz; b.w *= iz;
        ((float4*)slot_in)[o] = b;
    }
}

// ---------------------------------------------------------------------------
// Kernel 5: h = gelu(W1 @ slot_in + b1). grid 2048 (G11 grid-stride):
// 8192 waves x 8 rows each. 8 waves/SIMD occupancy.
// ---------------------------------------------------------------------------
__global__ __launch_bounds__(256) void k_mlp1(const float* __restrict__ W1,
                                              const float* __restrict__ b1,
                                              const float* __restrict__ slot_in,
                                              float* __restrict__ h) {
    const int wave = threadIdx.x >> 6, lane = threadIdx.x & 63;
    const int wid = blockIdx.x * 4 + wave;           // 0..8191
    for (int it = 0; it < 8; ++it) {
        const int row = wid + 8192 * it;             // e*1024 + j
        const int e = row >> 10;
        const float* wr = W1 + (size_t)row * D_DIM;
        const float* xr = slot_in + (size_t)e * D_DIM;
        float acc = 0.f;
        #pragma unroll
        for (int i = 0; i < 8; ++i) {
            int k = (lane + i * 64) * 4;
            float4 w4 = *(const float4*)(wr + k);
            float4 x4 = *(const float4*)(xr + k);
            acc += w4.x * x4.x + w4.y * x4.y + w4.z * x4.z + w4.w * x4.w;
        }
        #pragma unroll
        for (int off = 32; off; off >>= 1) acc += __shfl_xor(acc, off);
        if (lane == 0) {
            float v = acc + b1[row];
            h[row] = 0.5f * v * (1.f + erff(v * 0.70710678118654752f));
        }
    }
}

// Kernel 6: slot_out = W2 @ h + b2. grid 2048: 8192 waves x 16 rows.
__global__ __launch_bounds__(256) void k_mlp2(const float* __restrict__ W2,
                                              const float* __restrict__ b2,
                                              const float* __restrict__ h,
                                              float* __restrict__ slot_out) {
    const int wave = threadIdx.x >> 6, lane = threadIdx.x & 63;
    const int wid = blockIdx.x * 4 + wave;           // 0..8191
    for (int it = 0; it < 16; ++it) {
        const int row = wid + 8192 * it;             // e*2048 + d
        const int e = row >> 11;
        const float* wr = W2 + (size_t)row * H_DIM;
        const float* xr = h + (size_t)e * H_DIM;
        float acc = 0.f;
        #pragma unroll
        for (int i = 0; i < 4; ++i) {
            int k = (lane + i * 64) * 4;
            float4 w4 = *(const float4*)(wr + k);
            float4 x4 = *(const float4*)(xr + k);
            acc += w4.x * x4.x + w4.y * x4.y + w4.z * x4.z + w4.w * x4.w;
        }
        #pragma unroll
        for (int off = 32; off; off >>= 1) acc += __shfl_xor(acc, off);
        if (lane == 0) slot_out[row] = acc + b2[row];
    }
}

// ---------------------------------------------------------------------------
// Kernel 7: y[t] = (sum_s E[t][s]*so[s]) / (sum_s E[t][s]). Block 128x128.
// grid (16, 128). (R6-proven form.)
// ---------------------------------------------------------------------------
__global__ __launch_bounds__(256) void k_combine(const float* __restrict__ elog,
                                                 const float* __restrict__ so,
                                                 float* __restrict__ y) {
    __shared__ float cl[128][68];
    __shared__ float sol[64][128];
    __shared__ float rinv[128];
    const int tid = threadIdx.x;
    const int d0 = blockIdx.x * 128;
    const int tb = blockIdx.y * 128;
    const int tq = tid >> 4;    // 0..15
    const int dgq = tid & 15;   // 0..15
    #pragma unroll
    for (int ii = 0; ii < 8; ++ii) {          // stage E: 128x64
        int fi = tid + ii * 256; int r = fi >> 4, s4 = fi & 15;
        *(float4*)&cl[r][s4 * 4] =
            *(const float4*)&elog[(size_t)(tb + r) * NSLOT + s4 * 4];
    }
    #pragma unroll
    for (int ii = 0; ii < 8; ++ii) {          // stage slot_out tile 64x128
        int fi = tid + ii * 256; int r = fi >> 5, c4 = fi & 31;
        *(float4*)&sol[r][c4 * 4] =
            *(const float4*)&so[(size_t)r * D_DIM + d0 + c4 * 4];
    }
    __syncthreads();
    if (tid < 128) {                          // row sums -> 1/Z_t
        float zs = 0.f;
        #pragma unroll
        for (int q = 0; q < 16; ++q) {
            float4 v = *(const float4*)&cl[tid][q * 4];
            zs += v.x + v.y + v.z + v.w;
        }
        rinv[tid] = 1.f / zs;
    }
    __syncthreads();
    float4 acc0[8] = {}, acc1[8] = {};
    for (int s = 0; s < 64; ++s) {
        float4 sv0 = *(const float4*)&sol[s][dgq * 4];
        float4 sv1 = *(const float4*)&sol[s][64 + dgq * 4];
        #pragma unroll
        for (int i = 0; i < 8; ++i) {
            float cv = cl[tq + 16 * i][s];
            acc0[i].x += cv * sv0.x; acc0[i].y += cv * sv0.y;
            acc0[i].z += cv * sv0.z; acc0[i].w += cv * sv0.w;
            acc1[i].x += cv * sv1.x; acc1[i].y += cv * sv1.y;
            acc1[i].z += cv * sv1.z; acc1[i].w += cv * sv1.w;
        }
    }
    #pragma unroll
    for (int i = 0; i < 8; ++i) {
        float rz = rinv[tq + 16 * i];
        acc0[i].x *= rz; acc0[i].y *= rz; acc0[i].z *= rz; acc0[i].w *= rz;
        acc1[i].x *= rz; acc1[i].y *= rz; acc1[i].z *= rz; acc1[i].w *= rz;
        *(float4*)&y[(size_t)(tb + tq + 16 * i) * D_DIM + d0 + dgq * 4] = acc0[i];
        *(float4*)&y[(size_t)(tb + tq + 16 * i) * D_DIM + d0 + 64 + dgq * 4] = acc1[i];
    }
}

// ---------------------------------------------------------------------------
extern "C" void kernel_launch(void* const* d_in, const int* in_sizes, int n_in,
                              void* d_out, int out_size, void* d_ws, size_t ws_size,
                              hipStream_t stream) {
    const float* x  = (const float*)d_in[0];
    const float* Wd = (const float*)d_in[1];
    const float* W1 = (const float*)d_in[2];
    const float* b1 = (const float*)d_in[3];
    const float* W2 = (const float*)d_in[4];
    const float* b2 = (const float*)d_in[5];
    float* y = (float*)d_out;

    float* w = (float*)d_ws;
    float* plog     = w;                                      // 8*16384*64
    float* elog     = plog + (size_t)KSPLIT * T_TOK * NSLOT;  // 16384*64
    float* pz4      = elog + (size_t)T_TOK * NSLOT;           // 256 bins
    float* partial  = pz4 + 256;                              // 64*64*2048
    float* slot_in  = partial + (size_t)64 * NSLOT * D_DIM;   // 64*2048
    float* h        = slot_in + (size_t)NSLOT * D_DIM;        // 64*1024
    float* slot_out = h + (size_t)NSLOT * H_DIM;              // 64*2048

    k_logits<<<dim3(T_TOK / TBLK, KSPLIT), 256, 0, stream>>>(x, Wd, plog, pz4);
    k_lsum<<<1024, 256, 0, stream>>>(plog, elog, pz4);
    k_slot<<<dim3(8, 64), 256, 0, stream>>>(x, elog, partial);
    k_sred<<<512, 256, 0, stream>>>(partial, pz4, slot_in);
    k_mlp1<<<2048, 256, 0, stream>>>(W1, b1, slot_in, h);
    k_mlp2<<<2048, 256, 0, stream>>>(W2, b2, h, slot_out);
    k_combine<<<dim3(16, 128), 256, 0, stream>>>(elog, slot_out, y);
}